// Round 6
// baseline (116.799 us; speedup 1.0000x reference)
//
#include <hip/hip_runtime.h>

#define MAXL 33
#define PB 128   // blocks per batch image
#define TPB 128  // threads per block
#define NBLK (PB * 8)
#define GSTR (PB * TPB)  // grid stride in float4-groups

// ---------------------------------------------------------------------------
// Fully fused: segmented per-(batch,label) sums + final pairwise loss in ONE
// kernel. Per-thread private LDS histograms (f32 sums / u32 counts, odd dword
// stride 33 -> conflict-free banks). Main loop: 8-pixel units, software-
// pipelined 1 unit deep with static A/B register ping-pong (10 loads in
// flight per wave). Epilogue: block flush to non-atomic partials, then a
// no-spin last-block ticket (device-scope fence + atomicAdd) elects ONE block
// to reduce all 528xPB partials and compute the pairwise log-loss. The
// finalize reads in a fixed order -> bitwise deterministic.
// ---------------------------------------------------------------------------
__global__ __launch_bounds__(TPB, 2) void disc_loss_fused_kernel(
    const float* __restrict__ pred, const int* __restrict__ labels,
    float* __restrict__ partial, unsigned* __restrict__ counter,
    float* __restrict__ out, int N) {
  const int b = blockIdx.y;
  const int ng = N >> 2;  // float4 groups per image (200704)
  __shared__ float sumh[TPB * MAXL];     // 16.9 KB
  __shared__ unsigned cnth[TPB * MAXL];  // 16.9 KB
  __shared__ float xred[2][2][MAXL];
  __shared__ float red[8 * 2 * MAXL];  // 528 final slots
  __shared__ float s_invden[8];
  __shared__ float s_part[2];
  __shared__ unsigned s_last;
  const int tid = threadIdx.x;

  float* sh = &sumh[tid * MAXL];
  unsigned* ch = &cnth[tid * MAXL];
#pragma unroll
  for (int i = 0; i < MAXL; ++i) {
    sh[i] = 0.f;
    ch[i] = 0u;
  }

  const float4* p = reinterpret_cast<const float4*>(pred) + (size_t)b * 4 * ng;
  const int4* lb = reinterpret_cast<const int4*>(labels) + (size_t)b * ng;
  const int start = blockIdx.x * TPB + tid;

  auto ld = [&](int g, float4& c0, float4& c1, float4& c2, float4& c3,
                int4& l) {
    c0 = p[g];
    c1 = p[g + ng];
    c2 = p[g + 2 * ng];
    c3 = p[g + 3 * ng];
    l = lb[g];
  };
  auto proc = [&](const float4& c0, const float4& c1, const float4& c2,
                  const float4& c3, const int4& l) {
    float s0 = c0.x * c0.x + c1.x * c1.x + c2.x * c2.x + c3.x * c3.x;
    float s1 = c0.y * c0.y + c1.y * c1.y + c2.y * c2.y + c3.y * c3.y;
    float s2 = c0.z * c0.z + c1.z * c1.z + c2.z * c2.z + c3.z * c3.z;
    float s3 = c0.w * c0.w + c1.w * c1.w + c2.w * c2.w + c3.w * c3.w;
    const bool e01 = l.x == l.y, e02 = l.x == l.z, e03 = l.x == l.w;
    const bool e12 = l.y == l.z, e13 = l.y == l.w, e23 = l.z == l.w;
    const float w1 = s1 + (e01 ? s0 : 0.f);
    const float w2 = s2 + (e12 ? s1 : 0.f) + (e02 ? s0 : 0.f);
    const float w3 =
        s3 + (e23 ? s2 : 0.f) + (e13 ? s1 : 0.f) + (e03 ? s0 : 0.f);
    const unsigned m1 = 1u + (unsigned)e01;
    const unsigned m2 = 1u + (unsigned)e12 + (unsigned)e02;
    const unsigned m3 = 1u + (unsigned)e23 + (unsigned)e13 + (unsigned)e03;
    // batched reads (one LDS round-trip), ordered writes (last wins)
    const float r0 = sh[l.x], r1 = sh[l.y], r2 = sh[l.z], r3 = sh[l.w];
    const unsigned q0 = ch[l.x], q1 = ch[l.y], q2 = ch[l.z], q3 = ch[l.w];
    sh[l.x] = r0 + s0;
    sh[l.y] = r1 + w1;
    sh[l.z] = r2 + w2;
    sh[l.w] = r3 + w3;
    ch[l.x] = q0 + 1u;
    ch[l.y] = q1 + m1;
    ch[l.z] = q2 + m2;
    ch[l.w] = q3 + m3;
  };

  // 12 or 13 4-pixel iterations per thread; uniform per block (blocks 0..31
  // of each row have start < 4096 -> 13). 6 8-pixel units + optional tail.
  const bool has4 = (start + 12 * GSTR) < ng;

  float4 a0, a1, a2, a3, a4, a5, a6, a7;
  float4 b0, b1, b2, b3, b4, b5, b6, b7;
  int4 al, al2, bl, bl2;

  ld(start, a0, a1, a2, a3, al);              // unit 0, iter 0
  ld(start + GSTR, a4, a5, a6, a7, al2);      // unit 0, iter 1
#pragma unroll
  for (int k = 0; k < 3; ++k) {
    const int bb = start + (4 * k + 2) * GSTR;  // unit 2k+1
    ld(bb, b0, b1, b2, b3, bl);
    ld(bb + GSTR, b4, b5, b6, b7, bl2);
    proc(a0, a1, a2, a3, al);
    proc(a4, a5, a6, a7, al2);
    if (k < 2) {
      const int ab = start + (4 * k + 4) * GSTR;  // unit 2k+2
      ld(ab, a0, a1, a2, a3, al);
      ld(ab + GSTR, a4, a5, a6, a7, al2);
    } else if (has4) {
      ld(start + 12 * GSTR, a0, a1, a2, a3, al);  // tail iter 12
    }
    proc(b0, b1, b2, b3, bl);
    proc(b4, b5, b6, b7, bl2);
  }
  if (has4) proc(a0, a1, a2, a3, al);
  __syncthreads();

  // block flush: wave w reduces thread-slices w*64 .. w*64+63
  const int wave = tid >> 6;
  const int lane = tid & 63;
  if (lane < MAXL) {
    float fs = 0.f;
    unsigned fc = 0u;
#pragma unroll 8
    for (int u = 0; u < 64; ++u) {
      fs += sumh[(wave * 64 + u) * MAXL + lane];
      fc += cnth[(wave * 64 + u) * MAXL + lane];
    }
    xred[wave][0][lane] = fs;
    xred[wave][1][lane] = (float)fc;
  }
  __syncthreads();
  if (tid < MAXL) {
    partial[(size_t)(b * 2 * MAXL + tid) * PB + blockIdx.x] =
        xred[0][0][tid] + xred[1][0][tid];
    partial[(size_t)(b * 2 * MAXL + MAXL + tid) * PB + blockIdx.x] =
        xred[0][1][tid] + xred[1][1][tid];
  }
  __syncthreads();  // all partial stores done block-wide
  __threadfence();  // release: make them device-visible before the ticket
  if (tid == 0) {
    unsigned t = atomicAdd(counter, 1u);
    s_last = (t == NBLK - 1) ? 1u : 0u;
  }
  __syncthreads();
  if (s_last == 0u) return;

  // ---- last-arriving block: finalize (deterministic fixed-order reads) ----
  __threadfence();  // acquire: see all blocks' partials
  for (int slot = tid; slot < 8 * 2 * MAXL; slot += TPB) {
    const float4* row =
        reinterpret_cast<const float4*>(partial) + (size_t)slot * (PB / 4);
    float acc0 = 0.f, acc1 = 0.f;
#pragma unroll 8
    for (int u = 0; u < PB / 4; u += 2) {
      float4 x = row[u], y = row[u + 1];
      acc0 += x.x + x.y + x.z + x.w;
      acc1 += y.x + y.y + y.z + y.w;
    }
    red[slot] = acc0 + acc1;
  }
  __syncthreads();
  if (tid < 8) {
    int nk = 0;
    for (int l = MAXL - 1; l >= 1; --l) {
      if (red[tid * 2 * MAXL + MAXL + l] > 0.f) {
        nk = l;
        break;
      }
    }
    s_invden[tid] = (nk > 1) ? 1.f / ((float)nk * ((float)nk - 1.f)) : 0.f;
  }
  __syncthreads();
  float local = 0.f;
  for (int idx = tid; idx < 8 * MAXL * MAXL; idx += TPB) {
    int bb = idx / (MAXL * MAXL);
    int r = idx - bb * MAXL * MAXL;
    int i = r / MAXL;
    int j = r - i * MAXL;
    if (i >= 1 && i < j) {
      float ci = red[bb * 2 * MAXL + MAXL + i];
      float cj = red[bb * 2 * MAXL + MAXL + j];
      if (ci > 0.f && cj > 0.f) {
        float si = red[bb * 2 * MAXL + i] / (ci * ci);
        float sj = red[bb * 2 * MAXL + j] / (cj * cj);
        float d = 3.0f - sqrtf(si + sj);
        local += logf(d * d + 1.f) * s_invden[bb];
      }
    }
  }
  for (int off = 32; off; off >>= 1) local += __shfl_down(local, off, 64);
  if (lane == 0) s_part[wave] = local;
  __syncthreads();
  if (tid == 0) out[0] = s_part[0] + s_part[1];
}

extern "C" void kernel_launch(void* const* d_in, const int* in_sizes, int n_in,
                              void* d_out, int out_size, void* d_ws,
                              size_t ws_size, hipStream_t stream) {
  const float* pred = (const float*)d_in[0];
  // d_in[1] = kernels_mask: unused by the reference math -> never read.
  const int* labels = (const int*)d_in[2];
  float* out = (float*)d_out;

  const int B = 8;
  const int N = in_sizes[2] / B;  // 896*896 = 802816

  float* partial = (float*)d_ws;  // 528 slots x PB floats = 270336 B
  unsigned* counter = (unsigned*)((char*)d_ws + 528 * PB * sizeof(float));
  hipMemsetAsync(counter, 0, sizeof(unsigned), stream);  // fresh ticket/call

  dim3 grid(PB, B);  // 1024 blocks of 128 threads, 4 blocks/CU (LDS-limited)
  disc_loss_fused_kernel<<<grid, dim3(TPB), 0, stream>>>(pred, labels, partial,
                                                         counter, out, N);
}

// Round 7
// 40.004 us; speedup vs baseline: 2.9197x; 2.9197x over previous
//
#include <hip/hip_runtime.h>

#define MAXL 33
#define CSTR 36  // u8 count-slice stride (9 dwords, dword-aligned per thread)
#define PB 128   // blocks per batch image
#define TPB 128  // threads per block

// ---------------------------------------------------------------------------
// Kernel 1: per-(batch,label) segmented sums, no atomics anywhere.
// Per-THREAD private LDS histograms: f32 sums (odd dword stride 33 ->
// conflict-free banks) and u8 counts (stride 36 bytes = 9 dwords; max count
// per thread-label is 13 iters * 4 px = 52 < 255). u8 counts shrink block
// LDS from 33.8 KB -> ~22 KB: 7 blocks/CU = 14 waves/CU (was 4/8) for the
// latency-bound main loop. Per 4-pixel iteration: batch-read the bins (one
// LDS round-trip), merge duplicate labels in registers via pairwise eq-masks
// (writes in pixel order; DS pipe is in-order per wave -> last write wins),
// batch-write. Global loads register double-buffered one iteration ahead.
// NOTE (R6 lesson): do NOT fuse the finalize via ticket+__threadfence();
// 1024 per-block device-scope fences cost ~110 us in L2 maintenance. The
// kernel boundary is the cheap fence.
// ---------------------------------------------------------------------------
__global__ __launch_bounds__(TPB, 3) void seg_hist_kernel(
    const float* __restrict__ pred, const int* __restrict__ labels,
    float* __restrict__ partial, int N) {
  const int b = blockIdx.y;
  const int ng = N >> 2;  // float4 groups per image
  __shared__ float sumh[TPB * MAXL];        // 16896 B
  __shared__ unsigned char cnth[TPB * CSTR];  // 4608 B
  __shared__ float xred[2][2][MAXL];        // 528 B
  const int tid = threadIdx.x;

  float* sh = &sumh[tid * MAXL];
  unsigned char* ch = &cnth[tid * CSTR];
#pragma unroll
  for (int i = 0; i < MAXL; ++i) sh[i] = 0.f;
#pragma unroll
  for (int i = 0; i < CSTR / 4; ++i)
    reinterpret_cast<unsigned*>(ch)[i] = 0u;

  const float4* p = reinterpret_cast<const float4*>(pred) + (size_t)b * 4 * ng;
  const int4* lb = reinterpret_cast<const int4*>(labels) + (size_t)b * ng;
  const int STRIDE = PB * TPB;

  int g = blockIdx.x * TPB + tid;  // always < ng on first iter
  float4 c0 = p[g], c1 = p[g + ng], c2 = p[g + 2 * ng], c3 = p[g + 3 * ng];
  int4 l = lb[g];

  while (true) {
    const int gn = g + STRIDE;
    const bool more = gn < ng;
    float4 n0, n1, n2, n3;
    int4 nl;
    if (more) {  // prefetch next iteration
      n0 = p[gn];
      n1 = p[gn + ng];
      n2 = p[gn + 2 * ng];
      n3 = p[gn + 3 * ng];
      nl = lb[gn];
    }

    // per-pixel sum over channels
    float s0 = c0.x * c0.x + c1.x * c1.x + c2.x * c2.x + c3.x * c3.x;
    float s1 = c0.y * c0.y + c1.y * c1.y + c2.y * c2.y + c3.y * c3.y;
    float s2 = c0.z * c0.z + c1.z * c1.z + c2.z * c2.z + c3.z * c3.z;
    float s3 = c0.w * c0.w + c1.w * c1.w + c2.w * c2.w + c3.w * c3.w;

    // duplicate-label merge masks
    const bool e01 = l.x == l.y, e02 = l.x == l.z, e03 = l.x == l.w;
    const bool e12 = l.y == l.z, e13 = l.y == l.w, e23 = l.z == l.w;
    const float w1 = s1 + (e01 ? s0 : 0.f);
    const float w2 = s2 + (e12 ? s1 : 0.f) + (e02 ? s0 : 0.f);
    const float w3 =
        s3 + (e23 ? s2 : 0.f) + (e13 ? s1 : 0.f) + (e03 ? s0 : 0.f);
    const unsigned m1 = 1u + (unsigned)e01;
    const unsigned m2 = 1u + (unsigned)e12 + (unsigned)e02;
    const unsigned m3 = 1u + (unsigned)e23 + (unsigned)e13 + (unsigned)e03;

    // batched reads (one LDS round-trip), then ordered writes (last wins)
    const float r0 = sh[l.x], r1 = sh[l.y], r2 = sh[l.z], r3 = sh[l.w];
    const unsigned q0 = ch[l.x], q1 = ch[l.y], q2 = ch[l.z], q3 = ch[l.w];
    sh[l.x] = r0 + s0;
    sh[l.y] = r1 + w1;
    sh[l.z] = r2 + w2;
    sh[l.w] = r3 + w3;
    ch[l.x] = (unsigned char)(q0 + 1u);
    ch[l.y] = (unsigned char)(q1 + m1);
    ch[l.z] = (unsigned char)(q2 + m2);
    ch[l.w] = (unsigned char)(q3 + m3);

    if (!more) break;
    c0 = n0;
    c1 = n1;
    c2 = n2;
    c3 = n3;
    l = nl;
    g = gn;
  }
  __syncthreads();

  const int wave = tid >> 6;
  const int lane = tid & 63;
  if (lane < MAXL) {  // wave w reduces thread-slices w*64 .. w*64+63
    float fs = 0.f;
    unsigned fc = 0u;
#pragma unroll 8
    for (int u = 0; u < 64; ++u) {
      fs += sumh[(wave * 64 + u) * MAXL + lane];
      fc += (unsigned)cnth[(wave * 64 + u) * CSTR + lane];
    }
    xred[wave][0][lane] = fs;
    xred[wave][1][lane] = (float)fc;
  }
  __syncthreads();
  if (tid < MAXL) {
    partial[(size_t)(b * 2 * MAXL + tid) * PB + blockIdx.x] =
        xred[0][0][tid] + xred[1][0][tid];
    partial[(size_t)(b * 2 * MAXL + MAXL + tid) * PB + blockIdx.x] =
        xred[0][1][tid] + xred[1][1][tid];
  }
}

// ---------------------------------------------------------------------------
// Kernel 2 (1 block, 512 threads): slot-per-thread row sums of the partials
// (no shuffle chains, independent float4 loads), then s = ssq/card^2,
// nk = max present label, pairwise log-loss.
// ---------------------------------------------------------------------------
__global__ __launch_bounds__(512) void reduce_finalize_kernel(
    const float* __restrict__ partial, float* __restrict__ out) {
  __shared__ float red[8 * 2 * MAXL];  // 528 slots
  __shared__ float s_val[8 * MAXL];
  __shared__ float s_flag[8 * MAXL];
  __shared__ float s_invden[8];
  __shared__ float s_part[8];
  const int tid = threadIdx.x;
  const int wave = tid >> 6;
  const int lane = tid & 63;

  {
    int slot = tid;
    const float4* row =
        reinterpret_cast<const float4*>(partial) + (size_t)slot * (PB / 4);
    float a0 = 0.f, a1 = 0.f;
#pragma unroll 8
    for (int u = 0; u < PB / 4; u += 2) {
      float4 x = row[u], y = row[u + 1];
      a0 += x.x + x.y + x.z + x.w;
      a1 += y.x + y.y + y.z + y.w;
    }
    if (slot < 8 * 2 * MAXL) red[slot] = a0 + a1;
  }
  if (tid < 8 * 2 * MAXL - 512) {
    int slot = 512 + tid;
    const float4* row =
        reinterpret_cast<const float4*>(partial) + (size_t)slot * (PB / 4);
    float a0 = 0.f, a1 = 0.f;
#pragma unroll 8
    for (int u = 0; u < PB / 4; u += 2) {
      float4 x = row[u], y = row[u + 1];
      a0 += x.x + x.y + x.z + x.w;
      a1 += y.x + y.y + y.z + y.w;
    }
    red[slot] = a0 + a1;
  }
  __syncthreads();

  for (int i = tid; i < 8 * MAXL; i += 512) {
    int b = i / MAXL, l = i - b * MAXL;
    float cnt = red[b * 2 * MAXL + MAXL + l];
    float ssq = red[b * 2 * MAXL + l];
    float safe = cnt > 0.f ? cnt : 1.f;
    s_val[i] = ssq / (safe * safe);
    s_flag[i] = (l >= 1 && cnt > 0.f) ? 1.f : 0.f;
  }
  __syncthreads();
  if (tid < 8) {
    int nk = 0;
    for (int l = MAXL - 1; l >= 0; --l) {
      if (red[tid * 2 * MAXL + MAXL + l] > 0.f) {
        nk = l;
        break;
      }
    }
    s_invden[tid] = (nk > 1) ? 1.f / ((float)nk * ((float)nk - 1.f)) : 0.f;
  }
  __syncthreads();

  float local = 0.f;
  const int total = 8 * MAXL * MAXL;
  for (int idx = tid; idx < total; idx += 512) {
    int b = idx / (MAXL * MAXL);
    int r = idx - b * MAXL * MAXL;
    int i = r / MAXL;
    int j = r - i * MAXL;
    if (i < j && s_flag[b * MAXL + i] != 0.f && s_flag[b * MAXL + j] != 0.f) {
      float S = s_val[b * MAXL + i] + s_val[b * MAXL + j];
      float d = 3.0f - sqrtf(S);
      local += logf(d * d + 1.f) * s_invden[b];
    }
  }
  for (int off = 32; off; off >>= 1) local += __shfl_down(local, off, 64);
  if (lane == 0) s_part[wave] = local;
  __syncthreads();
  if (tid == 0) {
    float tot = 0.f;
    for (int w = 0; w < 8; ++w) tot += s_part[w];
    out[0] = tot;
  }
}

extern "C" void kernel_launch(void* const* d_in, const int* in_sizes, int n_in,
                              void* d_out, int out_size, void* d_ws,
                              size_t ws_size, hipStream_t stream) {
  const float* pred = (const float*)d_in[0];
  // d_in[1] = kernels_mask: unused by the reference math -> never read.
  const int* labels = (const int*)d_in[2];
  float* out = (float*)d_out;

  const int B = 8;
  const int N = in_sizes[2] / B;  // 896*896 = 802816

  float* partial = (float*)d_ws;  // 528 slots x PB floats = 270 KB

  dim3 grid(PB, B);  // 1024 blocks of 128 threads, ~7 blocks/CU (LDS-limited)
  seg_hist_kernel<<<grid, dim3(TPB), 0, stream>>>(pred, labels, partial, N);
  reduce_finalize_kernel<<<dim3(1), dim3(512), 0, stream>>>(partial, out);
}

// Round 8
// 39.583 us; speedup vs baseline: 2.9508x; 1.0106x over previous
//
#include <hip/hip_runtime.h>

#define MAXL 33
#define CSTR 36  // u8 count-slice stride (9 dwords, dword-aligned per thread)
#define PB 128   // blocks per batch image
#define TPB 128  // threads per block
#define GSTR (PB * TPB)  // grid stride in float4-groups (16384)

// ---------------------------------------------------------------------------
// Kernel 1: per-(batch,label) segmented sums, no atomics anywhere.
// Per-THREAD private LDS histograms: f32 sums (odd dword stride 33 ->
// conflict-free banks) and u8 counts (stride 36 B; max per-thread-label
// count is 13*4 = 52 < 255). Per 4-pixel slot: batch-read bins (one LDS
// round-trip), merge duplicate labels in registers via pairwise eq-masks
// (writes in pixel order; DS pipe is in-order per wave -> last write wins),
// batch-write.
// THIS ROUND'S single change: software pipeline deepened to DEPTH 3 with a
// fully static 13-slot schedule over three register buffers A/B/C (15 VMEM
// loads ~ 240 B/lane in flight vs 5 before). Theory: k1 was VMEM-latency
// bound at depth 1 (each iter drained its own 5 loads; ~250 cy of work vs
// ~500 cy L3 latency). Slot 12 is predicated (blocks 0..31 only), so the
// schedule is uniform per block and register indexing is compile-time.
// NOTE (R6 lesson): do NOT fuse finalize via ticket+__threadfence(); 1024
// device-scope fences cost ~110 us. The kernel boundary is the cheap fence.
// ---------------------------------------------------------------------------
__global__ __launch_bounds__(TPB, 2) void seg_hist_kernel(
    const float* __restrict__ pred, const int* __restrict__ labels,
    float* __restrict__ partial, int N) {
  const int b = blockIdx.y;
  const int ng = N >> 2;  // float4 groups per image (200704)
  __shared__ float sumh[TPB * MAXL];          // 16896 B
  __shared__ unsigned char cnth[TPB * CSTR];  // 4608 B
  __shared__ float xred[2][2][MAXL];          // 528 B
  const int tid = threadIdx.x;

  float* sh = &sumh[tid * MAXL];
  unsigned char* ch = &cnth[tid * CSTR];
#pragma unroll
  for (int i = 0; i < MAXL; ++i) sh[i] = 0.f;
#pragma unroll
  for (int i = 0; i < CSTR / 4; ++i) reinterpret_cast<unsigned*>(ch)[i] = 0u;

  const float4* p = reinterpret_cast<const float4*>(pred) + (size_t)b * 4 * ng;
  const int4* lb = reinterpret_cast<const int4*>(labels) + (size_t)b * ng;
  const int start = blockIdx.x * TPB + tid;
  // 13 slots for blocks 0..31 (start < 4096), else 12; uniform per block.
  const bool has13 = (start + 12 * GSTR) < ng;

  auto ld = [&](int g, float4& c0, float4& c1, float4& c2, float4& c3,
                int4& l) {
    c0 = p[g];
    c1 = p[g + ng];
    c2 = p[g + 2 * ng];
    c3 = p[g + 3 * ng];
    l = lb[g];
  };
  auto proc = [&](const float4& c0, const float4& c1, const float4& c2,
                  const float4& c3, const int4& l) {
    float s0 = c0.x * c0.x + c1.x * c1.x + c2.x * c2.x + c3.x * c3.x;
    float s1 = c0.y * c0.y + c1.y * c1.y + c2.y * c2.y + c3.y * c3.y;
    float s2 = c0.z * c0.z + c1.z * c1.z + c2.z * c2.z + c3.z * c3.z;
    float s3 = c0.w * c0.w + c1.w * c1.w + c2.w * c2.w + c3.w * c3.w;
    const bool e01 = l.x == l.y, e02 = l.x == l.z, e03 = l.x == l.w;
    const bool e12 = l.y == l.z, e13 = l.y == l.w, e23 = l.z == l.w;
    const float w1 = s1 + (e01 ? s0 : 0.f);
    const float w2 = s2 + (e12 ? s1 : 0.f) + (e02 ? s0 : 0.f);
    const float w3 =
        s3 + (e23 ? s2 : 0.f) + (e13 ? s1 : 0.f) + (e03 ? s0 : 0.f);
    const unsigned m1 = 1u + (unsigned)e01;
    const unsigned m2 = 1u + (unsigned)e12 + (unsigned)e02;
    const unsigned m3 = 1u + (unsigned)e23 + (unsigned)e13 + (unsigned)e03;
    const float r0 = sh[l.x], r1 = sh[l.y], r2 = sh[l.z], r3 = sh[l.w];
    const unsigned q0 = ch[l.x], q1 = ch[l.y], q2 = ch[l.z], q3 = ch[l.w];
    sh[l.x] = r0 + s0;
    sh[l.y] = r1 + w1;
    sh[l.z] = r2 + w2;
    sh[l.w] = r3 + w3;
    ch[l.x] = (unsigned char)(q0 + 1u);
    ch[l.y] = (unsigned char)(q1 + m1);
    ch[l.z] = (unsigned char)(q2 + m2);
    ch[l.w] = (unsigned char)(q3 + m3);
  };

  float4 A0, A1, A2, A3, B0, B1, B2, B3, C0, C1, C2, C3;
  int4 Al, Bl, Cl;

  // prologue: fill the 3-deep pipeline
  ld(start + 0 * GSTR, A0, A1, A2, A3, Al);
  ld(start + 1 * GSTR, B0, B1, B2, B3, Bl);
  ld(start + 2 * GSTR, C0, C1, C2, C3, Cl);

#pragma unroll
  for (int k = 0; k < 3; ++k) {  // slots 3k .. 3k+2 processed, 3k+3..3k+5 loaded
    proc(A0, A1, A2, A3, Al);
    ld(start + (3 * k + 3) * GSTR, A0, A1, A2, A3, Al);
    proc(B0, B1, B2, B3, Bl);
    ld(start + (3 * k + 4) * GSTR, B0, B1, B2, B3, Bl);
    proc(C0, C1, C2, C3, Cl);
    ld(start + (3 * k + 5) * GSTR, C0, C1, C2, C3, Cl);
  }
  // tail: slots 9..11 (+ predicated slot 12)
  proc(A0, A1, A2, A3, Al);
  if (has13) ld(start + 12 * GSTR, A0, A1, A2, A3, Al);
  proc(B0, B1, B2, B3, Bl);
  proc(C0, C1, C2, C3, Cl);
  if (has13) proc(A0, A1, A2, A3, Al);
  __syncthreads();

  const int wave = tid >> 6;
  const int lane = tid & 63;
  if (lane < MAXL) {  // wave w reduces thread-slices w*64 .. w*64+63
    float fs = 0.f;
    unsigned fc = 0u;
#pragma unroll 8
    for (int u = 0; u < 64; ++u) {
      fs += sumh[(wave * 64 + u) * MAXL + lane];
      fc += (unsigned)cnth[(wave * 64 + u) * CSTR + lane];
    }
    xred[wave][0][lane] = fs;
    xred[wave][1][lane] = (float)fc;
  }
  __syncthreads();
  if (tid < MAXL) {
    partial[(size_t)(b * 2 * MAXL + tid) * PB + blockIdx.x] =
        xred[0][0][tid] + xred[1][0][tid];
    partial[(size_t)(b * 2 * MAXL + MAXL + tid) * PB + blockIdx.x] =
        xred[0][1][tid] + xred[1][1][tid];
  }
}

// ---------------------------------------------------------------------------
// Kernel 2 (1 block, 512 threads): slot-per-thread row sums of the partials
// (independent float4 loads), then s = ssq/card^2, nk = max present label,
// pairwise log-loss.
// ---------------------------------------------------------------------------
__global__ __launch_bounds__(512) void reduce_finalize_kernel(
    const float* __restrict__ partial, float* __restrict__ out) {
  __shared__ float red[8 * 2 * MAXL];  // 528 slots
  __shared__ float s_val[8 * MAXL];
  __shared__ float s_flag[8 * MAXL];
  __shared__ float s_invden[8];
  __shared__ float s_part[8];
  const int tid = threadIdx.x;
  const int wave = tid >> 6;
  const int lane = tid & 63;

  {
    int slot = tid;
    const float4* row =
        reinterpret_cast<const float4*>(partial) + (size_t)slot * (PB / 4);
    float a0 = 0.f, a1 = 0.f;
#pragma unroll 8
    for (int u = 0; u < PB / 4; u += 2) {
      float4 x = row[u], y = row[u + 1];
      a0 += x.x + x.y + x.z + x.w;
      a1 += y.x + y.y + y.z + y.w;
    }
    if (slot < 8 * 2 * MAXL) red[slot] = a0 + a1;
  }
  if (tid < 8 * 2 * MAXL - 512) {
    int slot = 512 + tid;
    const float4* row =
        reinterpret_cast<const float4*>(partial) + (size_t)slot * (PB / 4);
    float a0 = 0.f, a1 = 0.f;
#pragma unroll 8
    for (int u = 0; u < PB / 4; u += 2) {
      float4 x = row[u], y = row[u + 1];
      a0 += x.x + x.y + x.z + x.w;
      a1 += y.x + y.y + y.z + y.w;
    }
    red[slot] = a0 + a1;
  }
  __syncthreads();

  for (int i = tid; i < 8 * MAXL; i += 512) {
    int b = i / MAXL, l = i - b * MAXL;
    float cnt = red[b * 2 * MAXL + MAXL + l];
    float ssq = red[b * 2 * MAXL + l];
    float safe = cnt > 0.f ? cnt : 1.f;
    s_val[i] = ssq / (safe * safe);
    s_flag[i] = (l >= 1 && cnt > 0.f) ? 1.f : 0.f;
  }
  __syncthreads();
  if (tid < 8) {
    int nk = 0;
    for (int l = MAXL - 1; l >= 0; --l) {
      if (red[tid * 2 * MAXL + MAXL + l] > 0.f) {
        nk = l;
        break;
      }
    }
    s_invden[tid] = (nk > 1) ? 1.f / ((float)nk * ((float)nk - 1.f)) : 0.f;
  }
  __syncthreads();

  float local = 0.f;
  const int total = 8 * MAXL * MAXL;
  for (int idx = tid; idx < total; idx += 512) {
    int b = idx / (MAXL * MAXL);
    int r = idx - b * MAXL * MAXL;
    int i = r / MAXL;
    int j = r - i * MAXL;
    if (i < j && s_flag[b * MAXL + i] != 0.f && s_flag[b * MAXL + j] != 0.f) {
      float S = s_val[b * MAXL + i] + s_val[b * MAXL + j];
      float d = 3.0f - sqrtf(S);
      local += logf(d * d + 1.f) * s_invden[b];
    }
  }
  for (int off = 32; off; off >>= 1) local += __shfl_down(local, off, 64);
  if (lane == 0) s_part[wave] = local;
  __syncthreads();
  if (tid == 0) {
    float tot = 0.f;
    for (int w = 0; w < 8; ++w) tot += s_part[w];
    out[0] = tot;
  }
}

extern "C" void kernel_launch(void* const* d_in, const int* in_sizes, int n_in,
                              void* d_out, int out_size, void* d_ws,
                              size_t ws_size, hipStream_t stream) {
  const float* pred = (const float*)d_in[0];
  // d_in[1] = kernels_mask: unused by the reference math -> never read.
  const int* labels = (const int*)d_in[2];
  float* out = (float*)d_out;

  const int B = 8;
  const int N = in_sizes[2] / B;  // 896*896 = 802816

  float* partial = (float*)d_ws;  // 528 slots x PB floats = 270 KB

  dim3 grid(PB, B);  // 1024 blocks of 128 threads, 4 blocks/CU
  seg_hist_kernel<<<grid, dim3(TPB), 0, stream>>>(pred, labels, partial, N);
  reduce_finalize_kernel<<<dim3(1), dim3(512), 0, stream>>>(partial, out);
}